// Round 2
// baseline (3597.191 us; speedup 1.0000x reference)
//
#include <hip/hip_runtime.h>
#include <cmath>

// Problem constants
#define BATCH 128
#define KCH 32
#define IMHW 80

// ---------------------------------------------------------------------------
// Block-wide reductions (256 threads = 4 waves of 64)
// ---------------------------------------------------------------------------
__device__ __forceinline__ float block_sum(float v, float* red) {
    for (int off = 32; off; off >>= 1) v += __shfl_xor(v, off);
    __syncthreads();
    if ((threadIdx.x & 63) == 0) red[threadIdx.x >> 6] = v;
    __syncthreads();
    return red[0] + red[1] + red[2] + red[3];
}

__device__ __forceinline__ float block_max(float v, float* red) {
    for (int off = 32; off; off >>= 1) v = fmaxf(v, __shfl_xor(v, off));
    __syncthreads();
    if ((threadIdx.x & 63) == 0) red[threadIdx.x >> 6] = v;
    __syncthreads();
    return fmaxf(fmaxf(red[0], red[1]), fmaxf(red[2], red[3]));
}

// ---------------------------------------------------------------------------
// 3x3 VALID conv, fp32. 16x16 output tile per block (256 threads).
// 4 oc-groups (one per wave) x 64 px threads (8x8), each thread 2x2 px.
// Weights staged ONCE per block into LDS [c][kpos][32] and read as
// wave-uniform broadcast (ds_read_b128, conflict-free). Input staged in
// CCH-channel chunks at ILD=20 (row bases py*20%32 all distinct -> 2-way
// free). Grid-stride over tiles to amortize weight staging.
// ---------------------------------------------------------------------------
template<int CIN, int COUT, int INHW, int OUTHW, bool RELU, int CCH, int MINW>
__global__ __launch_bounds__(256, MINW) void conv3x3_kernel(
    const float* __restrict__ in, const float* __restrict__ w,
    const float* __restrict__ bias, float* __restrict__ out, int ntiles)
{
    constexpr int NT   = (OUTHW + 15) / 16;  // 5
    constexpr int ILD  = 20;                 // padded leading dim (bank-clean)
    constexpr int ROWS = 18;
    constexpr int CSZ  = ROWS * ILD;         // 360 floats per channel
    constexpr int GC   = (COUT + 3) / 4;

    __shared__ float wlds[CIN * 9 * 32];
    __shared__ float ild[CCH * CSZ];

    const int tid = threadIdx.x;

    // ---- stage all weights once per block (coalesced src, LDS scatter) ----
    for (int j = tid; j < CIN * 9 * COUT; j += 256) {
        int oc = j / (CIN * 9);
        int r  = j % (CIN * 9);          // = c*9 + kpos
        wlds[r * 32 + oc] = w[j];
    }
    if constexpr (4 * GC > COUT) {       // zero-pad unused oc slots
        constexpr int PAD = 32 - COUT;
        for (int j = tid; j < CIN * 9 * PAD; j += 256) {
            int r  = j / PAD;
            int oc = COUT + j % PAD;
            wlds[r * 32 + oc] = 0.f;
        }
    }

    const int g   = __builtin_amdgcn_readfirstlane(tid >> 6);
    const int p   = tid & 63;
    const int px  = p & 7, py = p >> 3;
    const int oc0 = g * GC;

    for (int t = blockIdx.x; t < ntiles; t += gridDim.x) {
        const int b   = t / (NT * NT);
        const int tt  = t % (NT * NT);
        const int ty0 = (tt / NT) * 16, tx0 = (tt % NT) * 16;
        const float* inb = in + (size_t)b * CIN * INHW * INHW;

        float acc[GC][2][2] = {};

        for (int c0 = 0; c0 < CIN; c0 += CCH) {
            __syncthreads();   // previous readers of ild done (also covers wlds 1st time)
            for (int i = tid; i < CCH * CSZ; i += 256) {
                int c = i / CSZ, r = i % CSZ;
                int iy = r / ILD, ix = r % ILD;
                if (ix < ROWS) {
                    int gy = min(ty0 + iy, INHW - 1);
                    int gx = min(tx0 + ix, INHW - 1);
                    ild[i] = inb[((size_t)(c0 + c) * INHW + gy) * INHW + gx];
                }
            }
            __syncthreads();

            for (int cc = 0; cc < CCH; ++cc) {
                const float* lin = ild + cc * CSZ;
                const float* wl  = wlds + (size_t)(c0 + cc) * 9 * 32;
#pragma unroll
                for (int ky = 0; ky < 3; ky++) {
#pragma unroll
                    for (int kx = 0; kx < 3; kx++) {
                        float v00 = lin[(py     + ky) * ILD + px     + kx];
                        float v01 = lin[(py     + ky) * ILD + px + 8 + kx];
                        float v10 = lin[(py + 8 + ky) * ILD + px     + kx];
                        float v11 = lin[(py + 8 + ky) * ILD + px + 8 + kx];
                        const float* wk = wl + (ky * 3 + kx) * 32 + oc0;
#pragma unroll
                        for (int q = 0; q < GC; q++) {
                            float wv = wk[q];       // wave-uniform broadcast
                            acc[q][0][0] = fmaf(wv, v00, acc[q][0][0]);
                            acc[q][0][1] = fmaf(wv, v01, acc[q][0][1]);
                            acc[q][1][0] = fmaf(wv, v10, acc[q][1][0]);
                            acc[q][1][1] = fmaf(wv, v11, acc[q][1][1]);
                        }
                    }
                }
            }
        }

        float* outb = out + (size_t)b * COUT * OUTHW * OUTHW;
#pragma unroll
        for (int q = 0; q < GC; q++) {
            int oc = oc0 + q;
            if (oc >= COUT) break;
            float bv = bias[oc];
#pragma unroll
            for (int yy = 0; yy < 2; yy++) {
                int y = ty0 + py + yy * 8;
                if (y >= OUTHW) continue;
#pragma unroll
                for (int xx = 0; xx < 2; xx++) {
                    int x = tx0 + px + xx * 8;
                    if (x >= OUTHW) continue;
                    float v = acc[q][yy][xx] + bv;
                    if (RELU) v = fmaxf(v, 0.f);
                    outb[((size_t)oc * OUTHW + y) * OUTHW + x] = v;
                }
            }
        }
    }
}

// conv(x - 0.33) == conv(x) with bias' = bias - 0.33 * sum(weights[oc])
__global__ void prep_bias_kernel(const float* __restrict__ w1,
                                 const float* __restrict__ b1,
                                 float* __restrict__ badj)
{
    int oc = threadIdx.x;
    if (oc < 20) {
        float s = 0.f;
        for (int i = 0; i < 27; i++) s += w1[oc * 27 + i];
        badj[oc] = b1[oc] - 0.33f * s;
    }
}

// ---------------------------------------------------------------------------
// Fused bilinear 74->80 upsample + T=400 softmax + soft-argmax
// ---------------------------------------------------------------------------
__global__ __launch_bounds__(256) void softargmax_kernel(
    const float* __restrict__ dense,
    float* __restrict__ mapOut,
    float* __restrict__ kpOut,
    const float* __restrict__ chg,
    float* __restrict__ overlapOut)
{
    __shared__ float ld_d[74 * 74];
    __shared__ float ld_e[6400];
    __shared__ int   ld_i0[80];
    __shared__ int   ld_i1[80];
    __shared__ float ld_f[80];
    __shared__ float red[4];

    const int tid = threadIdx.x;
    const int bk  = blockIdx.x;
    const int bloc = bk >> 5;

    const float* d = dense + (size_t)bk * 5476;
    for (int i = tid; i < 5476; i += 256) ld_d[i] = d[i];
    if (tid < 80) {
        float s  = ((float)tid + 0.5f) * (74.0f / 80.0f) - 0.5f;
        float fl = floorf(s);
        int   i0 = (int)fl;
        ld_i0[tid] = max(i0, 0);
        ld_i1[tid] = min(i0 + 1, 73);
        ld_f[tid]  = s - fl;
    }
    __syncthreads();

    float lmax = -1e30f;
#pragma unroll
    for (int it = 0; it < 25; it++) {
        int p  = tid + it * 256;
        int oy = p / 80, ox = p % 80;
        int y0 = ld_i0[oy], y1 = ld_i1[oy];
        float fy = ld_f[oy];
        int x0 = ld_i0[ox], x1 = ld_i1[ox];
        float fx = ld_f[ox];
        const float* r0 = ld_d + y0 * 74;
        const float* r1 = ld_d + y1 * 74;
        float a0 = r0[x0], a1 = r0[x1], b0 = r1[x0], b1 = r1[x1];
        float v0 = a0 + fx * (a1 - a0);
        float v1 = b0 + fx * (b1 - b0);
        float v  = v0 + fy * (v1 - v0);
        float lg = 400.0f * v;
        ld_e[p] = lg;
        lmax = fmaxf(lmax, lg);
    }
    float M = block_max(lmax, red);

    float s = 0.f, cx = 0.f, cy = 0.f, ov = 0.f;
    const float* chgb = chg ? (chg + (size_t)bloc * 6400) : nullptr;
#pragma unroll
    for (int it = 0; it < 25; it++) {
        int p = tid + it * 256;
        float e = __expf(ld_e[p] - M);
        ld_e[p] = e;
        s += e;
        int oy = p / 80, ox = p % 80;
        cx += e * (float)ox;
        cy += e * (float)oy;
        if (chgb) ov += e * chgb[p];
    }
    float S  = block_sum(s, red);
    float CX = block_sum(cx, red);
    float CY = block_sum(cy, red);
    float OV = chgb ? block_sum(ov, red) : 0.f;
    float inv = 1.0f / S;

    if (mapOut) {
        float* mo = mapOut + (size_t)bk * 6400;
#pragma unroll
        for (int it = 0; it < 25; it++) {
            int p = tid + it * 256;
            mo[p] = ld_e[p] * inv;
        }
    }
    if (tid == 0) {
        kpOut[(size_t)bk * 2]     = CX * inv;
        kpOut[(size_t)bk * 2 + 1] = CY * inv;
        if (overlapOut) overlapOut[bk] = OV * inv;
    }
}

// ---------------------------------------------------------------------------
__global__ __launch_bounds__(256) void imgchange_kernel(
    const float* __restrict__ first, const float* __restrict__ first_prev,
    float* __restrict__ chgOut, float* __restrict__ validOut)
{
    __shared__ float red[4];
    const int b = blockIdx.x, tid = threadIdx.x;
    const float* f  = first      + (size_t)b * 3 * 6400;
    const float* fp = first_prev + (size_t)b * 3 * 6400;
    float cnt = 0.f;
#pragma unroll
    for (int it = 0; it < 25; it++) {
        int p = tid + it * 256;
        float s = fabsf(fp[p] - f[p])
                + fabsf(fp[p + 6400] - f[p + 6400])
                + fabsf(fp[p + 12800] - f[p + 12800]);
        float c = (s > 0.f) ? 1.f : 0.f;
        chgOut[(size_t)b * 6400 + p] = c;
        cnt += c;
    }
    float tot = block_sum(cnt, red);
    if (tid == 0) validOut[b] = (tot > 0.f) ? 1.f : 0.f;
}

// ---------------------------------------------------------------------------
__global__ __launch_bounds__(256) void loss_kernel(
    const float* __restrict__ kp1, const float* __restrict__ kpp,
    const float* __restrict__ ov, const float* __restrict__ valid,
    float* __restrict__ lossOut)
{
    __shared__ float red[4];
    const int tid = threadIdx.x;

    float a = 0.f;
    for (int i = tid; i < BATCH * KCH; i += 256) {
        float dx = kp1[2 * i]     - kpp[2 * i];
        float dy = kp1[2 * i + 1] - kpp[2 * i + 1];
        a += dx * dx + dy * dy;
    }
    float kcl = block_sum(a, red) / (float)(BATCH * KCH);

    a = (tid < BATCH) ? valid[tid] : 0.f;
    float nv = fmaxf(block_sum(a, red), 1.0f);

    a = 0.f;
    for (int i = tid; i < BATCH * KCH; i += 256) {
        int b = i >> 5;
        a += valid[b] * (-logf(1e-7f + ov[i]));
    }
    float scl = block_sum(a, red) / (nv * (float)KCH);

    a = 0.f;
    if (tid < BATCH) {
        float so = 0.f;
        for (int k = 0; k < KCH; k++) so += ov[tid * KCH + k];
        a = valid[tid] * (-logf(1e-7f + so));
    }
    float ssl = block_sum(a, red) / nv;

    a = 0.f;
    for (int i = tid; i < BATCH * KCH; i += 256) {
        int b = i >> 5, kk = i & 31;
        float x = kp1[2 * i], y = kp1[2 * i + 1];
#pragma unroll
        for (int j = 0; j < 2; j++) {
            if (kk == j) continue;
            float xj = kp1[((size_t)b * KCH + j) * 2];
            float yj = kp1[((size_t)b * KCH + j) * 2 + 1];
            float dx = x - xj, dy = y - yj;
            float d2 = dx * dx + dy * dy;
            a += fmaxf(9.0f - d2, 0.0f);
        }
    }
    float kvl = block_sum(a, red) / (float)(KCH * KCH * BATCH);

    if (tid == 0) {
        lossOut[0] = kcl;
        lossOut[1] = scl;
        lossOut[2] = kvl;
        lossOut[3] = ssl;
    }
}

// ---------------------------------------------------------------------------
extern "C" void kernel_launch(void* const* d_in, const int* in_sizes, int n_in,
                              void* d_out, int out_size, void* d_ws, size_t ws_size,
                              hipStream_t stream)
{
    const float* first      = (const float*)d_in[0];
    const float* first_prev = (const float*)d_in[1];
    const float* second     = (const float*)d_in[2];
    const float* w1 = (const float*)d_in[3];
    const float* b1 = (const float*)d_in[4];
    const float* w2 = (const float*)d_in[5];
    const float* b2 = (const float*)d_in[6];
    const float* w3 = (const float*)d_in[7];
    const float* b3 = (const float*)d_in[8];
    float* out = (float*)d_out;
    float* ws  = (float*)d_ws;

    // output layout (floats)
    const size_t kp1Off  = 0;
    const size_t kp2Off  = (size_t)BATCH * KCH * 2;
    const size_t kppOff  = 2 * kp2Off;
    const size_t map1Off = 3 * kp2Off;
    const size_t mapSz   = (size_t)BATCH * KCH * IMHW * IMHW;
    const size_t map2Off = map1Off + mapSz;
    const size_t chgOff  = map2Off + mapSz;
    const size_t lossOff = chgOff + (size_t)BATCH * IMHW * IMHW;

    // workspace: [y2: Bc*30*76*76][shared y1/dense: Bc*32*74*74][overlap][valid][badj]
    const size_t y2PerB = 30 * 76 * 76;
    const size_t shPerB = 32 * 74 * 74;
    int Bc = BATCH;
    while (Bc > 1) {
        size_t need = ((size_t)Bc * (y2PerB + shPerB) + BATCH * KCH + BATCH + 32) * 4;
        if (need <= ws_size) break;
        Bc >>= 1;
    }
    const int nchunk = BATCH / Bc;
    float* ws_y2 = ws;
    float* ws_sh = ws + (size_t)Bc * y2PerB;
    float* ws_ov = ws_sh + (size_t)Bc * shPerB;
    float* ws_va = ws_ov + (size_t)BATCH * KCH;
    float* ws_ba = ws_va + BATCH;

    prep_bias_kernel<<<1, 32, 0, stream>>>(w1, b1, ws_ba);
    imgchange_kernel<<<BATCH, 256, 0, stream>>>(first, first_prev, out + chgOff, ws_va);

    const float* xin[3] = { first, first_prev, second };
    for (int ch = 0; ch < nchunk; ch++) {
        const int b0 = ch * Bc;
        const int ntiles = Bc * 25;
        const int grid = ntiles < 1600 ? ntiles : 1600;
        for (int s = 0; s < 3; s++) {
            const float* x = xin[s] + (size_t)b0 * 3 * IMHW * IMHW;
            conv3x3_kernel<3, 20, 80, 78, true, 3, 4>
                <<<grid, 256, 0, stream>>>(x, w1, ws_ba, ws_sh, ntiles);
            conv3x3_kernel<20, 30, 78, 76, true, 10, 4>
                <<<grid, 256, 0, stream>>>(ws_sh, w2, b2, ws_y2, ntiles);
            conv3x3_kernel<30, 32, 76, 74, false, 10, 3>
                <<<grid, 256, 0, stream>>>(ws_y2, w3, b3, ws_sh, ntiles);

            float* mapOut = nullptr;
            float* kpOut  = nullptr;
            const float* chg = nullptr;
            float* ovOut  = nullptr;
            if (s == 0) {
                mapOut = out + map1Off + (size_t)b0 * KCH * IMHW * IMHW;
                kpOut  = out + kp1Off  + (size_t)b0 * KCH * 2;
                chg    = out + chgOff  + (size_t)b0 * IMHW * IMHW;
                ovOut  = ws_ov + (size_t)b0 * KCH;
            } else if (s == 1) {
                kpOut  = out + kppOff + (size_t)b0 * KCH * 2;
            } else {
                mapOut = out + map2Off + (size_t)b0 * KCH * IMHW * IMHW;
                kpOut  = out + kp2Off  + (size_t)b0 * KCH * 2;
            }
            softargmax_kernel<<<Bc * KCH, 256, 0, stream>>>(ws_sh, mapOut, kpOut, chg, ovOut);
        }
    }

    loss_kernel<<<1, 256, 0, stream>>>(out + kp1Off, out + kppOff, ws_ov, ws_va, out + lossOff);
}

// Round 3
// 1968.472 us; speedup vs baseline: 1.8274x; 1.8274x over previous
//
#include <hip/hip_runtime.h>
#include <cmath>

// Problem constants
#define BATCH 128
#define KCH 32
#define IMHW 80

// ---------------------------------------------------------------------------
// Block-wide reductions (256 threads = 4 waves of 64)
// ---------------------------------------------------------------------------
__device__ __forceinline__ float block_sum(float v, float* red) {
    for (int off = 32; off; off >>= 1) v += __shfl_xor(v, off);
    __syncthreads();
    if ((threadIdx.x & 63) == 0) red[threadIdx.x >> 6] = v;
    __syncthreads();
    return red[0] + red[1] + red[2] + red[3];
}

__device__ __forceinline__ float block_max(float v, float* red) {
    for (int off = 32; off; off >>= 1) v = fmaxf(v, __shfl_xor(v, off));
    __syncthreads();
    if ((threadIdx.x & 63) == 0) red[threadIdx.x >> 6] = v;
    __syncthreads();
    return fmaxf(fmaxf(red[0], red[1]), fmaxf(red[2], red[3]));
}

// ---------------------------------------------------------------------------
// 3x3 VALID conv, fp32. ROUND-1 STRUCTURE: one 16x16 output tile per block,
// 4 oc-groups (one per wave) x 64 px threads (8x8), each thread 2x2 px.
// Round-3 changes vs round-1 (each with its own counter theory):
//  - ILD=20 (row bases py*20%32 = perfect 2-way -> free; 18 gave 3-way,
//    SQ_LDS_BANK_CONFLICT was 23% of conv3 cycles)
//  - WLDS: conv2/conv3 stage weights [c][kpos][oc32] in LDS once per block
//    (conv3 weights = 34.6KB > 16KB K$, s_load re-missed every c-iteration).
//    conv1 keeps s_load path (2.2KB fits K$; round-1 conv1 was fast).
// ---------------------------------------------------------------------------
template<int CIN, int COUT, int INHW, int OUTHW, bool RELU, bool SUB33, bool WLDS>
__global__ __launch_bounds__(256) void conv3x3_kernel(
    const float* __restrict__ in, const float* __restrict__ w,
    const float* __restrict__ bias, float* __restrict__ out)
{
    constexpr int NT   = (OUTHW + 15) / 16;  // 5
    constexpr int ILD  = 20;                 // bank-clean leading dim
    constexpr int ROWS = 18;
    constexpr int CSZ  = ROWS * ILD;         // 360 floats per channel
    constexpr int GC   = (COUT + 3) / 4;

    __shared__ float ld_in[CIN * CSZ];
    __shared__ float wlds[WLDS ? CIN * 9 * 32 : 1];

    const int tid = threadIdx.x;
    const int blk = blockIdx.x;
    const int b   = blk / (NT * NT);
    const int t   = blk % (NT * NT);
    const int ty0 = (t / NT) * 16, tx0 = (t % NT) * 16;

    if (WLDS) {
        // coalesced global read, LDS scatter (one-time; conflicts negligible)
        for (int j = tid; j < CIN * 9 * COUT; j += 256) {
            int oc = j / (CIN * 9);
            int r  = j % (CIN * 9);          // = c*9 + kpos
            wlds[r * 32 + oc] = w[j];
        }
        if constexpr (WLDS && (4 * GC > COUT)) {   // zero-pad unused oc slots
            constexpr int PAD = 32 - COUT;
            for (int j = tid; j < CIN * 9 * PAD; j += 256) {
                int r  = j / PAD;
                int oc = COUT + j % PAD;
                wlds[r * 32 + oc] = 0.f;
            }
        }
    }

    const float* inb = in + (size_t)b * CIN * INHW * INHW;
    for (int i = tid; i < CIN * CSZ; i += 256) {
        int c  = i / CSZ, r = i % CSZ;
        int iy = r / ILD, ix = r % ILD;
        if (ix < ROWS) {                    // cols 0..17 needed
            int gy = min(ty0 + iy, INHW - 1);
            int gx = min(tx0 + ix, INHW - 1);
            float v = inb[((size_t)c * INHW + gy) * INHW + gx];
            if (SUB33) v -= 0.33f;
            ld_in[i] = v;
        }
    }
    __syncthreads();

    const int g   = __builtin_amdgcn_readfirstlane(tid >> 6);
    const int p   = tid & 63;
    const int px  = p & 7, py = p >> 3;
    const int oc0 = g * GC;

    float acc[GC][2][2] = {};

    for (int c = 0; c < CIN; c++) {
        const float* lin = ld_in + c * CSZ;
        float wreg[WLDS ? 1 : GC][WLDS ? 1 : 9];
        if (!WLDS) {
#pragma unroll
            for (int q = 0; q < GC; q++) {
                int oc = min(oc0 + q, COUT - 1);
                const float* wp = w + ((size_t)oc * CIN + c) * 9;
#pragma unroll
                for (int kk = 0; kk < 9; kk++) wreg[q][kk] = wp[kk];
            }
        }
#pragma unroll
        for (int ky = 0; ky < 3; ky++) {
#pragma unroll
            for (int kx = 0; kx < 3; kx++) {
                float v00 = lin[(py     + ky) * ILD + px     + kx];
                float v01 = lin[(py     + ky) * ILD + px + 8 + kx];
                float v10 = lin[(py + 8 + ky) * ILD + px     + kx];
                float v11 = lin[(py + 8 + ky) * ILD + px + 8 + kx];
                const float* wk = WLDS ? (wlds + (c * 9 + ky * 3 + kx) * 32 + oc0)
                                       : nullptr;
#pragma unroll
                for (int q = 0; q < GC; q++) {
                    float wv = WLDS ? wk[q]                  // uniform broadcast
                                    : wreg[WLDS ? 0 : q][WLDS ? 0 : (ky * 3 + kx)];
                    acc[q][0][0] = fmaf(wv, v00, acc[q][0][0]);
                    acc[q][0][1] = fmaf(wv, v01, acc[q][0][1]);
                    acc[q][1][0] = fmaf(wv, v10, acc[q][1][0]);
                    acc[q][1][1] = fmaf(wv, v11, acc[q][1][1]);
                }
            }
        }
    }

    float* outb = out + (size_t)b * COUT * OUTHW * OUTHW;
#pragma unroll
    for (int q = 0; q < GC; q++) {
        int oc = oc0 + q;
        if (oc >= COUT) break;
        float bv = bias[oc];
#pragma unroll
        for (int yy = 0; yy < 2; yy++) {
            int y = ty0 + py + yy * 8;
            if (y >= OUTHW) continue;
#pragma unroll
            for (int xx = 0; xx < 2; xx++) {
                int x = tx0 + px + xx * 8;
                if (x >= OUTHW) continue;
                float v = acc[q][yy][xx] + bv;
                if (RELU) v = fmaxf(v, 0.f);
                outb[((size_t)oc * OUTHW + y) * OUTHW + x] = v;
            }
        }
    }
}

// ---------------------------------------------------------------------------
// Fused bilinear 74->80 upsample + T=400 softmax + soft-argmax
// ---------------------------------------------------------------------------
__global__ __launch_bounds__(256) void softargmax_kernel(
    const float* __restrict__ dense,
    float* __restrict__ mapOut,
    float* __restrict__ kpOut,
    const float* __restrict__ chg,
    float* __restrict__ overlapOut)
{
    __shared__ float ld_d[74 * 74];
    __shared__ float ld_e[6400];
    __shared__ int   ld_i0[80];
    __shared__ int   ld_i1[80];
    __shared__ float ld_f[80];
    __shared__ float red[4];

    const int tid = threadIdx.x;
    const int bk  = blockIdx.x;
    const int bloc = bk >> 5;

    const float* d = dense + (size_t)bk * 5476;
    for (int i = tid; i < 5476; i += 256) ld_d[i] = d[i];
    if (tid < 80) {
        float s  = ((float)tid + 0.5f) * (74.0f / 80.0f) - 0.5f;
        float fl = floorf(s);
        int   i0 = (int)fl;
        ld_i0[tid] = max(i0, 0);
        ld_i1[tid] = min(i0 + 1, 73);
        ld_f[tid]  = s - fl;
    }
    __syncthreads();

    float lmax = -1e30f;
#pragma unroll
    for (int it = 0; it < 25; it++) {
        int p  = tid + it * 256;
        int oy = p / 80, ox = p % 80;
        int y0 = ld_i0[oy], y1 = ld_i1[oy];
        float fy = ld_f[oy];
        int x0 = ld_i0[ox], x1 = ld_i1[ox];
        float fx = ld_f[ox];
        const float* r0 = ld_d + y0 * 74;
        const float* r1 = ld_d + y1 * 74;
        float a0 = r0[x0], a1 = r0[x1], b0 = r1[x0], b1 = r1[x1];
        float v0 = a0 + fx * (a1 - a0);
        float v1 = b0 + fx * (b1 - b0);
        float v  = v0 + fy * (v1 - v0);
        float lg = 400.0f * v;
        ld_e[p] = lg;
        lmax = fmaxf(lmax, lg);
    }
    float M = block_max(lmax, red);

    float s = 0.f, cx = 0.f, cy = 0.f, ov = 0.f;
    const float* chgb = chg ? (chg + (size_t)bloc * 6400) : nullptr;
#pragma unroll
    for (int it = 0; it < 25; it++) {
        int p = tid + it * 256;
        float e = __expf(ld_e[p] - M);
        ld_e[p] = e;
        s += e;
        int oy = p / 80, ox = p % 80;
        cx += e * (float)ox;
        cy += e * (float)oy;
        if (chgb) ov += e * chgb[p];
    }
    float S  = block_sum(s, red);
    float CX = block_sum(cx, red);
    float CY = block_sum(cy, red);
    float OV = chgb ? block_sum(ov, red) : 0.f;
    float inv = 1.0f / S;

    if (mapOut) {
        float* mo = mapOut + (size_t)bk * 6400;
#pragma unroll
        for (int it = 0; it < 25; it++) {
            int p = tid + it * 256;
            mo[p] = ld_e[p] * inv;
        }
    }
    if (tid == 0) {
        kpOut[(size_t)bk * 2]     = CX * inv;
        kpOut[(size_t)bk * 2 + 1] = CY * inv;
        if (overlapOut) overlapOut[bk] = OV * inv;
    }
}

// ---------------------------------------------------------------------------
__global__ __launch_bounds__(256) void imgchange_kernel(
    const float* __restrict__ first, const float* __restrict__ first_prev,
    float* __restrict__ chgOut, float* __restrict__ validOut)
{
    __shared__ float red[4];
    const int b = blockIdx.x, tid = threadIdx.x;
    const float* f  = first      + (size_t)b * 3 * 6400;
    const float* fp = first_prev + (size_t)b * 3 * 6400;
    float cnt = 0.f;
#pragma unroll
    for (int it = 0; it < 25; it++) {
        int p = tid + it * 256;
        float s = fabsf(fp[p] - f[p])
                + fabsf(fp[p + 6400] - f[p + 6400])
                + fabsf(fp[p + 12800] - f[p + 12800]);
        float c = (s > 0.f) ? 1.f : 0.f;
        chgOut[(size_t)b * 6400 + p] = c;
        cnt += c;
    }
    float tot = block_sum(cnt, red);
    if (tid == 0) validOut[b] = (tot > 0.f) ? 1.f : 0.f;
}

// ---------------------------------------------------------------------------
__global__ __launch_bounds__(256) void loss_kernel(
    const float* __restrict__ kp1, const float* __restrict__ kpp,
    const float* __restrict__ ov, const float* __restrict__ valid,
    float* __restrict__ lossOut)
{
    __shared__ float red[4];
    const int tid = threadIdx.x;

    float a = 0.f;
    for (int i = tid; i < BATCH * KCH; i += 256) {
        float dx = kp1[2 * i]     - kpp[2 * i];
        float dy = kp1[2 * i + 1] - kpp[2 * i + 1];
        a += dx * dx + dy * dy;
    }
    float kcl = block_sum(a, red) / (float)(BATCH * KCH);

    a = (tid < BATCH) ? valid[tid] : 0.f;
    float nv = fmaxf(block_sum(a, red), 1.0f);

    a = 0.f;
    for (int i = tid; i < BATCH * KCH; i += 256) {
        int b = i >> 5;
        a += valid[b] * (-logf(1e-7f + ov[i]));
    }
    float scl = block_sum(a, red) / (nv * (float)KCH);

    a = 0.f;
    if (tid < BATCH) {
        float so = 0.f;
        for (int k = 0; k < KCH; k++) so += ov[tid * KCH + k];
        a = valid[tid] * (-logf(1e-7f + so));
    }
    float ssl = block_sum(a, red) / nv;

    a = 0.f;
    for (int i = tid; i < BATCH * KCH; i += 256) {
        int b = i >> 5, kk = i & 31;
        float x = kp1[2 * i], y = kp1[2 * i + 1];
#pragma unroll
        for (int j = 0; j < 2; j++) {
            if (kk == j) continue;
            float xj = kp1[((size_t)b * KCH + j) * 2];
            float yj = kp1[((size_t)b * KCH + j) * 2 + 1];
            float dx = x - xj, dy = y - yj;
            float d2 = dx * dx + dy * dy;
            a += fmaxf(9.0f - d2, 0.0f);
        }
    }
    float kvl = block_sum(a, red) / (float)(KCH * KCH * BATCH);

    if (tid == 0) {
        lossOut[0] = kcl;
        lossOut[1] = scl;
        lossOut[2] = kvl;
        lossOut[3] = ssl;
    }
}

// ---------------------------------------------------------------------------
extern "C" void kernel_launch(void* const* d_in, const int* in_sizes, int n_in,
                              void* d_out, int out_size, void* d_ws, size_t ws_size,
                              hipStream_t stream)
{
    const float* first      = (const float*)d_in[0];
    const float* first_prev = (const float*)d_in[1];
    const float* second     = (const float*)d_in[2];
    const float* w1 = (const float*)d_in[3];
    const float* b1 = (const float*)d_in[4];
    const float* w2 = (const float*)d_in[5];
    const float* b2 = (const float*)d_in[6];
    const float* w3 = (const float*)d_in[7];
    const float* b3 = (const float*)d_in[8];
    float* out = (float*)d_out;
    float* ws  = (float*)d_ws;

    // output layout (floats)
    const size_t kp1Off  = 0;
    const size_t kp2Off  = (size_t)BATCH * KCH * 2;
    const size_t kppOff  = 2 * kp2Off;
    const size_t map1Off = 3 * kp2Off;
    const size_t mapSz   = (size_t)BATCH * KCH * IMHW * IMHW;
    const size_t map2Off = map1Off + mapSz;
    const size_t chgOff  = map2Off + mapSz;
    const size_t lossOff = chgOff + (size_t)BATCH * IMHW * IMHW;

    // workspace: [y2: Bc*30*76*76][shared y1/dense: Bc*32*74*74][overlap][valid]
    const size_t y2PerB = 30 * 76 * 76;
    const size_t shPerB = 32 * 74 * 74;
    int Bc = BATCH;
    while (Bc > 1) {
        size_t need = ((size_t)Bc * (y2PerB + shPerB) + BATCH * KCH + BATCH) * 4;
        if (need <= ws_size) break;
        Bc >>= 1;
    }
    const int nchunk = BATCH / Bc;
    float* ws_y2 = ws;
    float* ws_sh = ws + (size_t)Bc * y2PerB;
    float* ws_ov = ws_sh + (size_t)Bc * shPerB;
    float* ws_va = ws_ov + (size_t)BATCH * KCH;

    imgchange_kernel<<<BATCH, 256, 0, stream>>>(first, first_prev, out + chgOff, ws_va);

    const float* xin[3] = { first, first_prev, second };
    for (int ch = 0; ch < nchunk; ch++) {
        const int b0 = ch * Bc;
        for (int s = 0; s < 3; s++) {
            const float* x = xin[s] + (size_t)b0 * 3 * IMHW * IMHW;
            conv3x3_kernel<3, 20, 80, 78, true,  true,  false>
                <<<Bc * 25, 256, 0, stream>>>(x,     w1, b1, ws_sh);
            conv3x3_kernel<20, 30, 78, 76, true,  false, true>
                <<<Bc * 25, 256, 0, stream>>>(ws_sh, w2, b2, ws_y2);
            conv3x3_kernel<30, 32, 76, 74, false, false, true>
                <<<Bc * 25, 256, 0, stream>>>(ws_y2, w3, b3, ws_sh);

            float* mapOut = nullptr;
            float* kpOut  = nullptr;
            const float* chg = nullptr;
            float* ovOut  = nullptr;
            if (s == 0) {
                mapOut = out + map1Off + (size_t)b0 * KCH * IMHW * IMHW;
                kpOut  = out + kp1Off  + (size_t)b0 * KCH * 2;
                chg    = out + chgOff  + (size_t)b0 * IMHW * IMHW;
                ovOut  = ws_ov + (size_t)b0 * KCH;
            } else if (s == 1) {
                kpOut  = out + kppOff + (size_t)b0 * KCH * 2;
            } else {
                mapOut = out + map2Off + (size_t)b0 * KCH * IMHW * IMHW;
                kpOut  = out + kp2Off  + (size_t)b0 * KCH * 2;
            }
            softargmax_kernel<<<Bc * KCH, 256, 0, stream>>>(ws_sh, mapOut, kpOut, chg, ovOut);
        }
    }

    loss_kernel<<<1, 256, 0, stream>>>(out + kp1Off, out + kppOff, ws_ov, ws_va, out + lossOff);
}

// Round 6
// 1024.683 us; speedup vs baseline: 3.5105x; 1.9211x over previous
//
#include <hip/hip_runtime.h>
#include <cmath>

#define BATCH 128
#define KCH 32
#define IMHW 80

typedef __attribute__((ext_vector_type(8)))  short bf16x8;
typedef __attribute__((ext_vector_type(16))) float f32x16;
typedef __attribute__((ext_vector_type(4)))  unsigned short us4;

__device__ __forceinline__ unsigned short f2bf(float f) {
    unsigned int b = __float_as_uint(f);
    b += 0x7FFFu + ((b >> 16) & 1u);
    return (unsigned short)(b >> 16);
}

// ---------------------------------------------------------------------------
// Block-wide reductions (256 threads = 4 waves of 64)
// ---------------------------------------------------------------------------
__device__ __forceinline__ float block_sum(float v, float* red) {
    for (int off = 32; off; off >>= 1) v += __shfl_xor(v, off);
    __syncthreads();
    if ((threadIdx.x & 63) == 0) red[threadIdx.x >> 6] = v;
    __syncthreads();
    return red[0] + red[1] + red[2] + red[3];
}

__device__ __forceinline__ float block_max(float v, float* red) {
    for (int off = 32; off; off >>= 1) v = fmaxf(v, __shfl_xor(v, off));
    __syncthreads();
    if ((threadIdx.x & 63) == 0) red[threadIdx.x >> 6] = v;
    __syncthreads();
    return fmaxf(fmaxf(red[0], red[1]), fmaxf(red[2], red[3]));
}

// ---------------------------------------------------------------------------
// conv1: 3x3 VALID, CIN=3, COUT=20, fp32 compute (round-1 proven structure).
// Input fp32 NCHW [b][3][80][80]; output bf16 NHWC32 [b][78][78][32]
// (channels 20..31 pre-zeroed by memset).
// ---------------------------------------------------------------------------
__global__ __launch_bounds__(256) void conv1_kernel(
    const float* __restrict__ in, const float* __restrict__ w,
    const float* __restrict__ bias, unsigned short* __restrict__ out)
{
    constexpr int ILD = 18, ISZ = 18 * 18, GC = 5;

    __shared__ float ld_in[3 * ISZ];

    const int tid = threadIdx.x;
    const int blk = blockIdx.x;
    const int b   = blk / 25;
    const int t   = blk % 25;
    const int ty0 = (t / 5) * 16, tx0 = (t % 5) * 16;

    const float* inb = in + (size_t)b * 3 * 80 * 80;
    for (int i = tid; i < 3 * ISZ; i += 256) {
        int c  = i / ISZ, r = i % ISZ;
        int iy = r / ILD, ix = r % ILD;
        int gy = min(ty0 + iy, 79);
        int gx = min(tx0 + ix, 79);
        ld_in[i] = inb[((size_t)c * 80 + gy) * 80 + gx] - 0.33f;
    }
    __syncthreads();

    const int g   = __builtin_amdgcn_readfirstlane(tid >> 6);
    const int p   = tid & 63;
    const int px  = p & 7, py = p >> 3;
    const int oc0 = g * GC;

    float acc[GC][2][2] = {};

    for (int c = 0; c < 3; c++) {
        const float* lin = ld_in + c * ISZ;
        float wreg[GC][9];
#pragma unroll
        for (int q = 0; q < GC; q++) {
            const float* wp = w + ((size_t)(oc0 + q) * 3 + c) * 9;
#pragma unroll
            for (int kk = 0; kk < 9; kk++) wreg[q][kk] = wp[kk];
        }
#pragma unroll
        for (int ky = 0; ky < 3; ky++) {
#pragma unroll
            for (int kx = 0; kx < 3; kx++) {
                float v00 = lin[(py     + ky) * ILD + px     + kx];
                float v01 = lin[(py     + ky) * ILD + px + 8 + kx];
                float v10 = lin[(py + 8 + ky) * ILD + px     + kx];
                float v11 = lin[(py + 8 + ky) * ILD + px + 8 + kx];
#pragma unroll
                for (int q = 0; q < GC; q++) {
                    float wv = wreg[q][ky * 3 + kx];
                    acc[q][0][0] = fmaf(wv, v00, acc[q][0][0]);
                    acc[q][0][1] = fmaf(wv, v01, acc[q][0][1]);
                    acc[q][1][0] = fmaf(wv, v10, acc[q][1][0]);
                    acc[q][1][1] = fmaf(wv, v11, acc[q][1][1]);
                }
            }
        }
    }

    unsigned short* outb = out + (size_t)b * 78 * 78 * 32;
#pragma unroll
    for (int q = 0; q < GC; q++) {
        int oc = oc0 + q;
        float bv = bias[oc];
#pragma unroll
        for (int yy = 0; yy < 2; yy++) {
            int y = ty0 + py + yy * 8;
            if (y >= 78) continue;
#pragma unroll
            for (int xx = 0; xx < 2; xx++) {
                int x = tx0 + px + xx * 8;
                if (x >= 78) continue;
                float v = fmaxf(acc[q][yy][xx] + bv, 0.f);
                outb[((size_t)(y * 78 + x) << 5) + oc] = f2bf(v);
            }
        }
    }
}

// ---------------------------------------------------------------------------
// conv2/conv3 via bf16 MFMA 32x32x16. Input NHWC32 bf16; A=weights (M=oc),
// B=raw input tile (N=px col strip, K=channels). ky-reuse: one B-frag feeds
// 3 acc rows. Block = 32-col strip x RB(<=26) rows, 4 waves x <=8 rows.
// Out: bf16 NHWC32 (conv2) or fp32 NCHW (conv3 dense).
// ---------------------------------------------------------------------------
template<int INW, int OUTW, int CINR, int COUTR, bool RELU, bool F32OUT>
__global__ __launch_bounds__(256, 2) void convmfma_kernel(
    const unsigned short* __restrict__ in,
    const float* __restrict__ w,
    const float* __restrict__ bias,
    void* __restrict__ outv)
{
    __shared__ short wlds[9 * 2 * 2 * 32 * 8];   // [kpos][chh][g][oc][8ch] 18KB
    __shared__ short tile[34 * 34 * 16];         // [row][col][16ch] 37KB

    const int tid = threadIdx.x;
    const int blk = blockIdx.x;
    const int b  = blk / 9, t = blk % 9;
    const int ry = t / 3, sx = t % 3;
    const int x0 = sx * 32;
    const int q  = OUTW / 3, rm = OUTW % 3;
    const int rb0 = ry * q + min(ry, rm);
    const int RB  = q + (ry < rm ? 1 : 0);

    for (int i = tid; i < 9 * 2 * 2 * 32 * 8; i += 256) wlds[i] = 0;
    __syncthreads();
    for (int j = tid; j < COUTR * CINR * 9; j += 256) {
        int oc = j / (CINR * 9);
        int c  = (j / 9) % CINR;
        int kp = j % 9;
        int chh = c >> 4, g = (c >> 3) & 1, jc = c & 7;
        wlds[((((kp * 2 + chh) * 2 + g) * 32 + oc) << 3) + jc] = (short)f2bf(w[j]);
    }

    const int l   = tid & 63;
    const int wid = tid >> 6;
    const int lm  = l & 31;
    const int lg  = l >> 5;
    const int wr0 = wid * 8;
    const int nr  = max(0, min(8, RB - wr0));

    const unsigned short* inb = in + (size_t)b * INW * INW * 32;
    const bf16x8* wv = (const bf16x8*)wlds;
    const bf16x8* tv = (const bf16x8*)tile;

    f32x16 acc[8];
#pragma unroll
    for (int i = 0; i < 8; i++)
#pragma unroll
        for (int j = 0; j < 16; j++) acc[i][j] = 0.f;

    for (int chh = 0; chh < 2; chh++) {
        __syncthreads();
        const int nchunks = (RB + 2) * 34 * 2;
        for (int i = tid; i < nchunks; i += 256) {
            int h = i & 1, pxi = i >> 1;
            int ri = pxi / 34, ci = pxi % 34;
            int gy = rb0 + ri;
            int gx = min(x0 + ci, INW - 1);
            const float4* src = (const float4*)(inb + ((size_t)(gy * INW + gx) << 5) + chh * 16 + h * 8);
            *(float4*)(tile + ((ri * 34 + ci) * 16 + h * 8)) = *src;
        }
        __syncthreads();
#pragma unroll
        for (int kx = 0; kx < 3; kx++) {
            bf16x8 a0 = wv[(((kx    ) * 2 + chh) * 2 + lg) * 32 + lm];
            bf16x8 a1 = wv[(((kx + 3) * 2 + chh) * 2 + lg) * 32 + lm];
            bf16x8 a2 = wv[(((kx + 6) * 2 + chh) * 2 + lg) * 32 + lm];
#pragma unroll
            for (int tr = 0; tr < 10; tr++) {
                if (tr >= nr + 2) break;
                bf16x8 bfv = tv[((wr0 + tr) * 34 + kx + lm) * 2 + lg];
                if (tr < nr)
                    acc[tr]     = __builtin_amdgcn_mfma_f32_32x32x16_bf16(a0, bfv, acc[tr],     0, 0, 0);
                if (tr >= 1 && tr - 1 < nr)
                    acc[tr - 1] = __builtin_amdgcn_mfma_f32_32x32x16_bf16(a1, bfv, acc[tr - 1], 0, 0, 0);
                if (tr >= 2)
                    acc[tr - 2] = __builtin_amdgcn_mfma_f32_32x32x16_bf16(a2, bfv, acc[tr - 2], 0, 0, 0);
            }
        }
    }

    // Epilogue. C/D layout (HW-verified m74/m101): col = l&31 (=px),
    // row(oc) = (reg&3) + 8*(reg>>2) + 4*(l>>5).
    const int x = x0 + lm;
    if (F32OUT) {
        float* outp = (float*)outv + (size_t)b * COUTR * OUTW * OUTW;
#pragma unroll
        for (int tr = 0; tr < 8; tr++) {
            if (tr >= nr) break;
            int y = rb0 + wr0 + tr;
            if (x < OUTW) {
#pragma unroll
                for (int rg = 0; rg < 16; rg++) {
                    int oc = (rg & 3) + 8 * (rg >> 2) + 4 * lg;
                    outp[((size_t)oc * OUTW + y) * OUTW + x] = acc[tr][rg] + bias[oc];
                }
            }
        }
    } else {
        unsigned short* outp = (unsigned short*)outv + (size_t)b * OUTW * OUTW * 32;
#pragma unroll
        for (int tr = 0; tr < 8; tr++) {
            if (tr >= nr) break;
            int y = rb0 + wr0 + tr;
            if (x < OUTW) {
#pragma unroll
                for (int rq = 0; rq < 4; rq++) {
                    int ocb = rq * 8 + 4 * lg;
                    us4 pk;
#pragma unroll
                    for (int s = 0; s < 4; s++) {
                        int oc = ocb + s;
                        float v = (oc < COUTR) ? (acc[tr][rq * 4 + s] + bias[oc]) : 0.f;
                        if (RELU) v = fmaxf(v, 0.f);
                        pk[s] = f2bf(v);
                    }
                    *(us4*)(outp + ((size_t)(y * OUTW + x) << 5) + ocb) = pk;
                }
            }
        }
    }
}

// ---------------------------------------------------------------------------
// Fused bilinear 74->80 upsample + T=400 softmax + soft-argmax (unchanged)
// ---------------------------------------------------------------------------
__global__ __launch_bounds__(256) void softargmax_kernel(
    const float* __restrict__ dense,
    float* __restrict__ mapOut,
    float* __restrict__ kpOut,
    const float* __restrict__ chg,
    float* __restrict__ overlapOut)
{
    __shared__ float ld_d[74 * 74];
    __shared__ float ld_e[6400];
    __shared__ int   ld_i0[80];
    __shared__ int   ld_i1[80];
    __shared__ float ld_f[80];
    __shared__ float red[4];

    const int tid = threadIdx.x;
    const int bk  = blockIdx.x;
    const int bloc = bk >> 5;

    const float* d = dense + (size_t)bk * 5476;
    for (int i = tid; i < 5476; i += 256) ld_d[i] = d[i];
    if (tid < 80) {
        float s  = ((float)tid + 0.5f) * (74.0f / 80.0f) - 0.5f;
        float fl = floorf(s);
        int   i0 = (int)fl;
        ld_i0[tid] = max(i0, 0);
        ld_i1[tid] = min(i0 + 1, 73);
        ld_f[tid]  = s - fl;
    }
    __syncthreads();

    float lmax = -1e30f;
#pragma unroll
    for (int it = 0; it < 25; it++) {
        int p  = tid + it * 256;
        int oy = p / 80, ox = p % 80;
        int y0 = ld_i0[oy], y1 = ld_i1[oy];
        float fy = ld_f[oy];
        int x0 = ld_i0[ox], x1 = ld_i1[ox];
        float fx = ld_f[ox];
        const float* r0 = ld_d + y0 * 74;
        const float* r1 = ld_d + y1 * 74;
        float a0 = r0[x0], a1 = r0[x1], b0 = r1[x0], b1 = r1[x1];
        float v0 = a0 + fx * (a1 - a0);
        float v1 = b0 + fx * (b1 - b0);
        float v  = v0 + fy * (v1 - v0);
        float lg = 400.0f * v;
        ld_e[p] = lg;
        lmax = fmaxf(lmax, lg);
    }
    float M = block_max(lmax, red);

    float s = 0.f, cx = 0.f, cy = 0.f, ov = 0.f;
    const float* chgb = chg ? (chg + (size_t)bloc * 6400) : nullptr;
#pragma unroll
    for (int it = 0; it < 25; it++) {
        int p = tid + it * 256;
        float e = __expf(ld_e[p] - M);
        ld_e[p] = e;
        s += e;
        int oy = p / 80, ox = p % 80;
        cx += e * (float)ox;
        cy += e * (float)oy;
        if (chgb) ov += e * chgb[p];
    }
    float S  = block_sum(s, red);
    float CX = block_sum(cx, red);
    float CY = block_sum(cy, red);
    float OV = chgb ? block_sum(ov, red) : 0.f;
    float inv = 1.0f / S;

    if (mapOut) {
        float* mo = mapOut + (size_t)bk * 6400;
#pragma unroll
        for (int it = 0; it < 25; it++) {
            int p = tid + it * 256;
            mo[p] = ld_e[p] * inv;
        }
    }
    if (tid == 0) {
        kpOut[(size_t)bk * 2]     = CX * inv;
        kpOut[(size_t)bk * 2 + 1] = CY * inv;
        if (overlapOut) overlapOut[bk] = OV * inv;
    }
}

// ---------------------------------------------------------------------------
__global__ __launch_bounds__(256) void imgchange_kernel(
    const float* __restrict__ first, const float* __restrict__ first_prev,
    float* __restrict__ chgOut, float* __restrict__ validOut)
{
    __shared__ float red[4];
    const int b = blockIdx.x, tid = threadIdx.x;
    const float* f  = first      + (size_t)b * 3 * 6400;
    const float* fp = first_prev + (size_t)b * 3 * 6400;
    float cnt = 0.f;
#pragma unroll
    for (int it = 0; it < 25; it++) {
        int p = tid + it * 256;
        float s = fabsf(fp[p] - f[p])
                + fabsf(fp[p + 6400] - f[p + 6400])
                + fabsf(fp[p + 12800] - f[p + 12800]);
        float c = (s > 0.f) ? 1.f : 0.f;
        chgOut[(size_t)b * 6400 + p] = c;
        cnt += c;
    }
    float tot = block_sum(cnt, red);
    if (tid == 0) validOut[b] = (tot > 0.f) ? 1.f : 0.f;
}

// ---------------------------------------------------------------------------
__global__ __launch_bounds__(256) void loss_kernel(
    const float* __restrict__ kp1, const float* __restrict__ kpp,
    const float* __restrict__ ov, const float* __restrict__ valid,
    float* __restrict__ lossOut)
{
    __shared__ float red[4];
    const int tid = threadIdx.x;

    float a = 0.f;
    for (int i = tid; i < BATCH * KCH; i += 256) {
        float dx = kp1[2 * i]     - kpp[2 * i];
        float dy = kp1[2 * i + 1] - kpp[2 * i + 1];
        a += dx * dx + dy * dy;
    }
    float kcl = block_sum(a, red) / (float)(BATCH * KCH);

    a = (tid < BATCH) ? valid[tid] : 0.f;
    float nv = fmaxf(block_sum(a, red), 1.0f);

    a = 0.f;
    for (int i = tid; i < BATCH * KCH; i += 256) {
        int b = i >> 5;
        a += valid[b] * (-logf(1e-7f + ov[i]));
    }
    float scl = block_sum(a, red) / (nv * (float)KCH);

    a = 0.f;
    if (tid < BATCH) {
        float so = 0.f;
        for (int k = 0; k < KCH; k++) so += ov[tid * KCH + k];
        a = valid[tid] * (-logf(1e-7f + so));
    }
    float ssl = block_sum(a, red) / nv;

    a = 0.f;
    for (int i = tid; i < BATCH * KCH; i += 256) {
        int b = i >> 5, kk = i & 31;
        float x = kp1[2 * i], y = kp1[2 * i + 1];
#pragma unroll
        for (int j = 0; j < 2; j++) {
            if (kk == j) continue;
            float xj = kp1[((size_t)b * KCH + j) * 2];
            float yj = kp1[((size_t)b * KCH + j) * 2 + 1];
            float dx = x - xj, dy = y - yj;
            float d2 = dx * dx + dy * dy;
            a += fmaxf(9.0f - d2, 0.0f);
        }
    }
    float kvl = block_sum(a, red) / (float)(KCH * KCH * BATCH);

    if (tid == 0) {
        lossOut[0] = kcl;
        lossOut[1] = scl;
        lossOut[2] = kvl;
        lossOut[3] = ssl;
    }
}

// ---------------------------------------------------------------------------
extern "C" void kernel_launch(void* const* d_in, const int* in_sizes, int n_in,
                              void* d_out, int out_size, void* d_ws, size_t ws_size,
                              hipStream_t stream)
{
    const float* first      = (const float*)d_in[0];
    const float* first_prev = (const float*)d_in[1];
    const float* second     = (const float*)d_in[2];
    const float* w1 = (const float*)d_in[3];
    const float* b1 = (const float*)d_in[4];
    const float* w2 = (const float*)d_in[5];
    const float* b2 = (const float*)d_in[6];
    const float* w3 = (const float*)d_in[7];
    const float* b3 = (const float*)d_in[8];
    float* out = (float*)d_out;

    // output layout (floats)
    const size_t kp1Off  = 0;
    const size_t kp2Off  = (size_t)BATCH * KCH * 2;
    const size_t kppOff  = 2 * kp2Off;
    const size_t map1Off = 3 * kp2Off;
    const size_t mapSz   = (size_t)BATCH * KCH * IMHW * IMHW;
    const size_t map2Off = map1Off + mapSz;
    const size_t chgOff  = map2Off + mapSz;
    const size_t lossOff = chgOff + (size_t)BATCH * IMHW * IMHW;

    // workspace layout (bytes): y1 bf16 NHWC32 | y2 bf16 NHWC32 | dense f32 NCHW | ov | va
    const size_t y1PB = (size_t)78 * 78 * 32 * 2;   // 389376
    const size_t y2PB = (size_t)76 * 76 * 32 * 2;   // 369664
    const size_t dnPB = (size_t)32 * 74 * 74 * 4;   // 700928
    int Bc = BATCH;
    while (Bc > 1) {
        size_t need = (size_t)Bc * (y1PB + y2PB + dnPB) + (size_t)BATCH * KCH * 4 + 1024;
        if (need <= ws_size) break;
        Bc >>= 1;
    }
    const int nchunk = BATCH / Bc;
    char* wsb = (char*)d_ws;
    unsigned short* ws_y1 = (unsigned short*)wsb;
    unsigned short* ws_y2 = (unsigned short*)(wsb + (size_t)Bc * y1PB);
    float* ws_dn = (float*)(wsb + (size_t)Bc * (y1PB + y2PB));
    float* ws_ov = (float*)(wsb + (size_t)Bc * (y1PB + y2PB + dnPB));
    float* ws_va = ws_ov + (size_t)BATCH * KCH;

    // zero y1 pad channels (20..31) once; conv1 rewrites ch 0..19 every pass
    hipMemsetAsync(ws_y1, 0, (size_t)Bc * y1PB, stream);

    imgchange_kernel<<<BATCH, 256, 0, stream>>>(first, first_prev, out + chgOff, ws_va);

    const float* xin[3] = { first, first_prev, second };
    for (int ch = 0; ch < nchunk; ch++) {
        const int b0 = ch * Bc;
        for (int s = 0; s < 3; s++) {
            const float* x = xin[s] + (size_t)b0 * 3 * IMHW * IMHW;
            conv1_kernel<<<Bc * 25, 256, 0, stream>>>(x, w1, b1, ws_y1);
            convmfma_kernel<78, 76, 20, 30, true,  false>
                <<<Bc * 9, 256, 0, stream>>>(ws_y1, w2, b2, ws_y2);
            convmfma_kernel<76, 74, 30, 32, false, true>
                <<<Bc * 9, 256, 0, stream>>>(ws_y2, w3, b3, ws_dn);

            float* mapOut = nullptr;
            float* kpOut  = nullptr;
            const float* chg = nullptr;
            float* ovOut  = nullptr;
            if (s == 0) {
                mapOut = out + map1Off + (size_t)b0 * KCH * IMHW * IMHW;
                kpOut  = out + kp1Off  + (size_t)b0 * KCH * 2;
                chg    = out + chgOff  + (size_t)b0 * IMHW * IMHW;
                ovOut  = ws_ov + (size_t)b0 * KCH;
            } else if (s == 1) {
                kpOut  = out + kppOff + (size_t)b0 * KCH * 2;
            } else {
                mapOut = out + map2Off + (size_t)b0 * KCH * IMHW * IMHW;
                kpOut  = out + kp2Off  + (size_t)b0 * KCH * 2;
            }
            softargmax_kernel<<<Bc * KCH, 256, 0, stream>>>(ws_dn, mapOut, kpOut, chg, ovOut);
        }
    }

    loss_kernel<<<1, 256, 0, stream>>>(out + kp1Off, out + kppOff, ws_ov, ws_va, out + lossOff);
}

// Round 7
// 816.954 us; speedup vs baseline: 4.4032x; 1.2543x over previous
//
#include <hip/hip_runtime.h>
#include <cmath>

#define BATCH 128
#define KCH 32
#define IMHW 80

typedef __attribute__((ext_vector_type(8)))  short bf16x8;
typedef __attribute__((ext_vector_type(16))) float f32x16;
typedef __attribute__((ext_vector_type(4)))  unsigned short us4;

__device__ __forceinline__ unsigned short f2bf(float f) {
    unsigned int b = __float_as_uint(f);
    b += 0x7FFFu + ((b >> 16) & 1u);
    return (unsigned short)(b >> 16);
}

// ---------------------------------------------------------------------------
// Block-wide reductions (256 threads = 4 waves of 64)
// ---------------------------------------------------------------------------
__device__ __forceinline__ float block_sum(float v, float* red) {
    for (int off = 32; off; off >>= 1) v += __shfl_xor(v, off);
    __syncthreads();
    if ((threadIdx.x & 63) == 0) red[threadIdx.x >> 6] = v;
    __syncthreads();
    return red[0] + red[1] + red[2] + red[3];
}

__device__ __forceinline__ float block_max(float v, float* red) {
    for (int off = 32; off; off >>= 1) v = fmaxf(v, __shfl_xor(v, off));
    __syncthreads();
    if ((threadIdx.x & 63) == 0) red[threadIdx.x >> 6] = v;
    __syncthreads();
    return fmaxf(fmaxf(red[0], red[1]), fmaxf(red[2], red[3]));
}

// ---------------------------------------------------------------------------
// conv1: 3x3 VALID, CIN=3, COUT=20, fp32 compute (round-1 proven structure).
// Round-7 change: epilogue repacks via LDS st[256][22] (pad-22 breaks the
// py-stride bank collision) so each thread writes ONE pixel's full 64B
// (ch20..31 zero) as 4x uint4 coalesced stores. Eliminates the scattered
// 2B stores AND the 49.8MB pad-channel memset.
// ---------------------------------------------------------------------------
__global__ __launch_bounds__(256) void conv1_kernel(
    const float* __restrict__ in, const float* __restrict__ w,
    const float* __restrict__ bias, unsigned short* __restrict__ out)
{
    constexpr int ILD = 18, ISZ = 18 * 18, GC = 5;

    __shared__ float ld_in[3 * ISZ];
    __shared__ unsigned short st[256 * 22];

    const int tid = threadIdx.x;
    const int blk = blockIdx.x;
    const int b   = blk / 25;
    const int t   = blk % 25;
    const int ty0 = (t / 5) * 16, tx0 = (t % 5) * 16;

    const float* inb = in + (size_t)b * 3 * 80 * 80;
    for (int i = tid; i < 3 * ISZ; i += 256) {
        int c  = i / ISZ, r = i % ISZ;
        int iy = r / ILD, ix = r % ILD;
        int gy = min(ty0 + iy, 79);
        int gx = min(tx0 + ix, 79);
        ld_in[i] = inb[((size_t)c * 80 + gy) * 80 + gx] - 0.33f;
    }
    __syncthreads();

    const int g   = __builtin_amdgcn_readfirstlane(tid >> 6);
    const int p   = tid & 63;
    const int px  = p & 7, py = p >> 3;
    const int oc0 = g * GC;

    float acc[GC][2][2] = {};

    for (int c = 0; c < 3; c++) {
        const float* lin = ld_in + c * ISZ;
        float wreg[GC][9];
#pragma unroll
        for (int q = 0; q < GC; q++) {
            const float* wp = w + ((size_t)(oc0 + q) * 3 + c) * 9;
#pragma unroll
            for (int kk = 0; kk < 9; kk++) wreg[q][kk] = wp[kk];
        }
#pragma unroll
        for (int ky = 0; ky < 3; ky++) {
#pragma unroll
            for (int kx = 0; kx < 3; kx++) {
                float v00 = lin[(py     + ky) * ILD + px     + kx];
                float v01 = lin[(py     + ky) * ILD + px + 8 + kx];
                float v10 = lin[(py + 8 + ky) * ILD + px     + kx];
                float v11 = lin[(py + 8 + ky) * ILD + px + 8 + kx];
#pragma unroll
                for (int q = 0; q < GC; q++) {
                    float wv = wreg[q][ky * 3 + kx];
                    acc[q][0][0] = fmaf(wv, v00, acc[q][0][0]);
                    acc[q][0][1] = fmaf(wv, v01, acc[q][0][1]);
                    acc[q][1][0] = fmaf(wv, v10, acc[q][1][0]);
                    acc[q][1][1] = fmaf(wv, v11, acc[q][1][1]);
                }
            }
        }
    }

    // stage results to LDS [pixel][oc] (pad 22 -> write conflicts <=4-way)
#pragma unroll
    for (int q = 0; q < GC; q++) {
        int oc = oc0 + q;
        float bv = bias[oc];
#pragma unroll
        for (int yy = 0; yy < 2; yy++) {
#pragma unroll
            for (int xx = 0; xx < 2; xx++) {
                int pp = (py + yy * 8) * 16 + (px + xx * 8);
                st[pp * 22 + oc] = f2bf(fmaxf(acc[q][yy][xx] + bv, 0.f));
            }
        }
    }
    __syncthreads();

    // writeback: thread tid owns pixel tid; 64B contiguous (ch20..31 = 0)
    const int pp = tid;
    const int y = ty0 + (pp >> 4), x = tx0 + (pp & 15);
    if (y < 78 && x < 78) {
        unsigned int ow[16];
#pragma unroll
        for (int i = 0; i < 10; i++)
            ow[i] = (unsigned int)st[pp * 22 + 2 * i]
                  | ((unsigned int)st[pp * 22 + 2 * i + 1] << 16);
#pragma unroll
        for (int i = 10; i < 16; i++) ow[i] = 0;
        uint4* dst = (uint4*)(out + ((size_t)b * 78 * 78 + (size_t)(y * 78 + x)) * 32);
#pragma unroll
        for (int i = 0; i < 4; i++)
            dst[i] = make_uint4(ow[4 * i], ow[4 * i + 1], ow[4 * i + 2], ow[4 * i + 3]);
    }
}

// ---------------------------------------------------------------------------
// conv2/conv3 via bf16 MFMA 32x32x16 (unchanged from round 6 — control).
// ---------------------------------------------------------------------------
template<int INW, int OUTW, int CINR, int COUTR, bool RELU, bool F32OUT>
__global__ __launch_bounds__(256, 2) void convmfma_kernel(
    const unsigned short* __restrict__ in,
    const float* __restrict__ w,
    const float* __restrict__ bias,
    void* __restrict__ outv)
{
    __shared__ short wlds[9 * 2 * 2 * 32 * 8];   // [kpos][chh][g][oc][8ch] 18KB
    __shared__ short tile[34 * 34 * 16];         // [row][col][16ch] 37KB

    const int tid = threadIdx.x;
    const int blk = blockIdx.x;
    const int b  = blk / 9, t = blk % 9;
    const int ry = t / 3, sx = t % 3;
    const int x0 = sx * 32;
    const int q  = OUTW / 3, rm = OUTW % 3;
    const int rb0 = ry * q + min(ry, rm);
    const int RB  = q + (ry < rm ? 1 : 0);

    for (int i = tid; i < 9 * 2 * 2 * 32 * 8; i += 256) wlds[i] = 0;
    __syncthreads();
    for (int j = tid; j < COUTR * CINR * 9; j += 256) {
        int oc = j / (CINR * 9);
        int c  = (j / 9) % CINR;
        int kp = j % 9;
        int chh = c >> 4, g = (c >> 3) & 1, jc = c & 7;
        wlds[((((kp * 2 + chh) * 2 + g) * 32 + oc) << 3) + jc] = (short)f2bf(w[j]);
    }

    const int l   = tid & 63;
    const int wid = tid >> 6;
    const int lm  = l & 31;
    const int lg  = l >> 5;
    const int wr0 = wid * 8;
    const int nr  = max(0, min(8, RB - wr0));

    const unsigned short* inb = in + (size_t)b * INW * INW * 32;
    const bf16x8* wv = (const bf16x8*)wlds;
    const bf16x8* tv = (const bf16x8*)tile;

    f32x16 acc[8];
#pragma unroll
    for (int i = 0; i < 8; i++)
#pragma unroll
        for (int j = 0; j < 16; j++) acc[i][j] = 0.f;

    for (int chh = 0; chh < 2; chh++) {
        __syncthreads();
        const int nchunks = (RB + 2) * 34 * 2;
        for (int i = tid; i < nchunks; i += 256) {
            int h = i & 1, pxi = i >> 1;
            int ri = pxi / 34, ci = pxi % 34;
            int gy = rb0 + ri;
            int gx = min(x0 + ci, INW - 1);
            const float4* src = (const float4*)(inb + ((size_t)(gy * INW + gx) << 5) + chh * 16 + h * 8);
            *(float4*)(tile + ((ri * 34 + ci) * 16 + h * 8)) = *src;
        }
        __syncthreads();
#pragma unroll
        for (int kx = 0; kx < 3; kx++) {
            bf16x8 a0 = wv[(((kx    ) * 2 + chh) * 2 + lg) * 32 + lm];
            bf16x8 a1 = wv[(((kx + 3) * 2 + chh) * 2 + lg) * 32 + lm];
            bf16x8 a2 = wv[(((kx + 6) * 2 + chh) * 2 + lg) * 32 + lm];
#pragma unroll
            for (int tr = 0; tr < 10; tr++) {
                if (tr >= nr + 2) break;
                bf16x8 bfv = tv[((wr0 + tr) * 34 + kx + lm) * 2 + lg];
                if (tr < nr)
                    acc[tr]     = __builtin_amdgcn_mfma_f32_32x32x16_bf16(a0, bfv, acc[tr],     0, 0, 0);
                if (tr >= 1 && tr - 1 < nr)
                    acc[tr - 1] = __builtin_amdgcn_mfma_f32_32x32x16_bf16(a1, bfv, acc[tr - 1], 0, 0, 0);
                if (tr >= 2)
                    acc[tr - 2] = __builtin_amdgcn_mfma_f32_32x32x16_bf16(a2, bfv, acc[tr - 2], 0, 0, 0);
            }
        }
    }

    // Epilogue. C/D layout (HW-verified m74/m101): col = l&31 (=px),
    // row(oc) = (reg&3) + 8*(reg>>2) + 4*(l>>5).
    const int x = x0 + lm;
    if (F32OUT) {
        float* outp = (float*)outv + (size_t)b * COUTR * OUTW * OUTW;
#pragma unroll
        for (int tr = 0; tr < 8; tr++) {
            if (tr >= nr) break;
            int y = rb0 + wr0 + tr;
            if (x < OUTW) {
#pragma unroll
                for (int rg = 0; rg < 16; rg++) {
                    int oc = (rg & 3) + 8 * (rg >> 2) + 4 * lg;
                    outp[((size_t)oc * OUTW + y) * OUTW + x] = acc[tr][rg] + bias[oc];
                }
            }
        }
    } else {
        unsigned short* outp = (unsigned short*)outv + (size_t)b * OUTW * OUTW * 32;
#pragma unroll
        for (int tr = 0; tr < 8; tr++) {
            if (tr >= nr) break;
            int y = rb0 + wr0 + tr;
            if (x < OUTW) {
#pragma unroll
                for (int rq = 0; rq < 4; rq++) {
                    int ocb = rq * 8 + 4 * lg;
                    us4 pk;
#pragma unroll
                    for (int s = 0; s < 4; s++) {
                        int oc = ocb + s;
                        float v = (oc < COUTR) ? (acc[tr][rq * 4 + s] + bias[oc]) : 0.f;
                        if (RELU) v = fmaxf(v, 0.f);
                        pk[s] = f2bf(v);
                    }
                    *(us4*)(outp + ((size_t)(y * OUTW + x) << 5) + ocb) = pk;
                }
            }
        }
    }
}

// ---------------------------------------------------------------------------
// Fused bilinear 74->80 upsample + T=400 softmax + soft-argmax.
// Round-7: exp values live in 25 per-thread REGISTERS (statically indexed),
// ld_e LDS array removed -> LDS 54K->23K, occupancy 2->6 blocks/CU.
// ---------------------------------------------------------------------------
__global__ __launch_bounds__(256) void softargmax_kernel(
    const float* __restrict__ dense,
    float* __restrict__ mapOut,
    float* __restrict__ kpOut,
    const float* __restrict__ chg,
    float* __restrict__ overlapOut)
{
    __shared__ float ld_d[74 * 74];
    __shared__ int   ld_i0[80];
    __shared__ int   ld_i1[80];
    __shared__ float ld_f[80];
    __shared__ float red[4];

    const int tid = threadIdx.x;
    const int bk  = blockIdx.x;
    const int bloc = bk >> 5;

    const float* d = dense + (size_t)bk * 5476;
    for (int i = tid; i < 5476; i += 256) ld_d[i] = d[i];
    if (tid < 80) {
        float s  = ((float)tid + 0.5f) * (74.0f / 80.0f) - 0.5f;
        float fl = floorf(s);
        int   i0 = (int)fl;
        ld_i0[tid] = max(i0, 0);
        ld_i1[tid] = min(i0 + 1, 73);
        ld_f[tid]  = s - fl;
    }
    __syncthreads();

    float ev[25];
    float lmax = -1e30f;
#pragma unroll
    for (int it = 0; it < 25; it++) {
        int p  = tid + it * 256;
        int oy = p / 80, ox = p % 80;
        int y0 = ld_i0[oy], y1 = ld_i1[oy];
        float fy = ld_f[oy];
        int x0 = ld_i0[ox], x1 = ld_i1[ox];
        float fx = ld_f[ox];
        const float* r0 = ld_d + y0 * 74;
        const float* r1 = ld_d + y1 * 74;
        float a0 = r0[x0], a1 = r0[x1], b0 = r1[x0], b1 = r1[x1];
        float v0 = a0 + fx * (a1 - a0);
        float v1 = b0 + fx * (b1 - b0);
        float v  = v0 + fy * (v1 - v0);
        float lg = 400.0f * v;
        ev[it] = lg;
        lmax = fmaxf(lmax, lg);
    }
    float M = block_max(lmax, red);

    float s = 0.f, cx = 0.f, cy = 0.f, ov = 0.f;
    const float* chgb = chg ? (chg + (size_t)bloc * 6400) : nullptr;
#pragma unroll
    for (int it = 0; it < 25; it++) {
        int p = tid + it * 256;
        float e = __expf(ev[it] - M);
        ev[it] = e;
        s += e;
        int oy = p / 80, ox = p % 80;
        cx += e * (float)ox;
        cy += e * (float)oy;
        if (chgb) ov += e * chgb[p];
    }
    float S  = block_sum(s, red);
    float CX = block_sum(cx, red);
    float CY = block_sum(cy, red);
    float OV = chgb ? block_sum(ov, red) : 0.f;
    float inv = 1.0f / S;

    if (mapOut) {
        float* mo = mapOut + (size_t)bk * 6400;
#pragma unroll
        for (int it = 0; it < 25; it++) {
            int p = tid + it * 256;
            mo[p] = ev[it] * inv;
        }
    }
    if (tid == 0) {
        kpOut[(size_t)bk * 2]     = CX * inv;
        kpOut[(size_t)bk * 2 + 1] = CY * inv;
        if (overlapOut) overlapOut[bk] = OV * inv;
    }
}

// ---------------------------------------------------------------------------
// img_change: 4 blocks per batch (512 total); valid flag via atomicMax
// (validOut pre-zeroed by 512B memset).
// ---------------------------------------------------------------------------
__global__ __launch_bounds__(256) void imgchange_kernel(
    const float* __restrict__ first, const float* __restrict__ first_prev,
    float* __restrict__ chgOut, float* __restrict__ validOut)
{
    __shared__ float red[4];
    const int blk = blockIdx.x, tid = threadIdx.x;
    const int b = blk >> 2, seg = blk & 3;
    const int base = seg * 1600;
    const float* f  = first      + (size_t)b * 3 * 6400;
    const float* fp = first_prev + (size_t)b * 3 * 6400;
    float cnt = 0.f;
#pragma unroll
    for (int it = 0; it < 7; it++) {
        int i = tid + it * 256;
        if (i < 1600) {
            int p = base + i;
            float s = fabsf(fp[p] - f[p])
                    + fabsf(fp[p + 6400] - f[p + 6400])
                    + fabsf(fp[p + 12800] - f[p + 12800]);
            float c = (s > 0.f) ? 1.f : 0.f;
            chgOut[(size_t)b * 6400 + p] = c;
            cnt += c;
        }
    }
    float tot = block_sum(cnt, red);
    if (tid == 0 && tot > 0.f)
        atomicMax((int*)(validOut + b), __float_as_int(1.0f));
}

// ---------------------------------------------------------------------------
__global__ __launch_bounds__(256) void loss_kernel(
    const float* __restrict__ kp1, const float* __restrict__ kpp,
    const float* __restrict__ ov, const float* __restrict__ valid,
    float* __restrict__ lossOut)
{
    __shared__ float red[4];
    const int tid = threadIdx.x;

    float a = 0.f;
    for (int i = tid; i < BATCH * KCH; i += 256) {
        float dx = kp1[2 * i]     - kpp[2 * i];
        float dy = kp1[2 * i + 1] - kpp[2 * i + 1];
        a += dx * dx + dy * dy;
    }
    float kcl = block_sum(a, red) / (float)(BATCH * KCH);

    a = (tid < BATCH) ? valid[tid] : 0.f;
    float nv = fmaxf(block_sum(a, red), 1.0f);

    a = 0.f;
    for (int i = tid; i < BATCH * KCH; i += 256) {
        int b = i >> 5;
        a += valid[b] * (-logf(1e-7f + ov[i]));
    }
    float scl = block_sum(a, red) / (nv * (float)KCH);

    a = 0.f;
    if (tid < BATCH) {
        float so = 0.f;
        for (int k = 0; k < KCH; k++) so += ov[tid * KCH + k];
        a = valid[tid] * (-logf(1e-7f + so));
    }
    float ssl = block_sum(a, red) / nv;

    a = 0.f;
    for (int i = tid; i < BATCH * KCH; i += 256) {
        int b = i >> 5, kk = i & 31;
        float x = kp1[2 * i], y = kp1[2 * i + 1];
#pragma unroll
        for (int j = 0; j < 2; j++) {
            if (kk == j) continue;
            float xj = kp1[((size_t)b * KCH + j) * 2];
            float yj = kp1[((size_t)b * KCH + j) * 2 + 1];
            float dx = x - xj, dy = y - yj;
            float d2 = dx * dx + dy * dy;
            a += fmaxf(9.0f - d2, 0.0f);
        }
    }
    float kvl = block_sum(a, red) / (float)(KCH * KCH * BATCH);

    if (tid == 0) {
        lossOut[0] = kcl;
        lossOut[1] = scl;
        lossOut[2] = kvl;
        lossOut[3] = ssl;
    }
}

// ---------------------------------------------------------------------------
extern "C" void kernel_launch(void* const* d_in, const int* in_sizes, int n_in,
                              void* d_out, int out_size, void* d_ws, size_t ws_size,
                              hipStream_t stream)
{
    const float* first      = (const float*)d_in[0];
    const float* first_prev = (const float*)d_in[1];
    const float* second     = (const float*)d_in[2];
    const float* w1 = (const float*)d_in[3];
    const float* b1 = (const float*)d_in[4];
    const float* w2 = (const float*)d_in[5];
    const float* b2 = (const float*)d_in[6];
    const float* w3 = (const float*)d_in[7];
    const float* b3 = (const float*)d_in[8];
    float* out = (float*)d_out;

    // output layout (floats)
    const size_t kp1Off  = 0;
    const size_t kp2Off  = (size_t)BATCH * KCH * 2;
    const size_t kppOff  = 2 * kp2Off;
    const size_t map1Off = 3 * kp2Off;
    const size_t mapSz   = (size_t)BATCH * KCH * IMHW * IMHW;
    const size_t map2Off = map1Off + mapSz;
    const size_t chgOff  = map2Off + mapSz;
    const size_t lossOff = chgOff + (size_t)BATCH * IMHW * IMHW;

    // workspace layout (bytes): y1 bf16 NHWC32 | y2 bf16 NHWC32 | dense f32 NCHW | ov | va
    const size_t y1PB = (size_t)78 * 78 * 32 * 2;   // 389376
    const size_t y2PB = (size_t)76 * 76 * 32 * 2;   // 369664
    const size_t dnPB = (size_t)32 * 74 * 74 * 4;   // 700928
    int Bc = BATCH;
    while (Bc > 1) {
        size_t need = (size_t)Bc * (y1PB + y2PB + dnPB) + (size_t)BATCH * KCH * 4 + 1024;
        if (need <= ws_size) break;
        Bc >>= 1;
    }
    const int nchunk = BATCH / Bc;
    char* wsb = (char*)d_ws;
    unsigned short* ws_y1 = (unsigned short*)wsb;
    unsigned short* ws_y2 = (unsigned short*)(wsb + (size_t)Bc * y1PB);
    float* ws_dn = (float*)(wsb + (size_t)Bc * (y1PB + y2PB));
    float* ws_ov = (float*)(wsb + (size_t)Bc * (y1PB + y2PB + dnPB));
    float* ws_va = ws_ov + (size_t)BATCH * KCH;

    // zero the 128-float valid-flag array (atomicMax target)
    hipMemsetAsync(ws_va, 0, BATCH * sizeof(float), stream);

    imgchange_kernel<<<BATCH * 4, 256, 0, stream>>>(first, first_prev, out + chgOff, ws_va);

    const float* xin[3] = { first, first_prev, second };
    for (int ch = 0; ch < nchunk; ch++) {
        const int b0 = ch * Bc;
        for (int s = 0; s < 3; s++) {
            const float* x = xin[s] + (size_t)b0 * 3 * IMHW * IMHW;
            conv1_kernel<<<Bc * 25, 256, 0, stream>>>(x, w1, b1, ws_y1);
            convmfma_kernel<78, 76, 20, 30, true,  false>
                <<<Bc * 9, 256, 0, stream>>>(ws_y1, w2, b2, ws_y2);
            convmfma_kernel<76, 74, 30, 32, false, true>
                <<<Bc * 9, 256, 0, stream>>>(ws_y2, w3, b3, ws_dn);

            float* mapOut = nullptr;
            float* kpOut  = nullptr;
            const float* chg = nullptr;
            float* ovOut  = nullptr;
            if (s == 0) {
                mapOut = out + map1Off + (size_t)b0 * KCH * IMHW * IMHW;
                kpOut  = out + kp1Off  + (size_t)b0 * KCH * 2;
                chg    = out + chgOff  + (size_t)b0 * IMHW * IMHW;
                ovOut  = ws_ov + (size_t)b0 * KCH;
            } else if (s == 1) {
                kpOut  = out + kppOff + (size_t)b0 * KCH * 2;
            } else {
                mapOut = out + map2Off + (size_t)b0 * KCH * IMHW * IMHW;
                kpOut  = out + kp2Off  + (size_t)b0 * KCH * 2;
            }
            softargmax_kernel<<<Bc * KCH, 256, 0, stream>>>(ws_dn, mapOut, kpOut, chg, ovOut);
        }
    }

    loss_kernel<<<1, 256, 0, stream>>>(out + kp1Off, out + kppOff, ws_ov, ws_va, out + lossOff);
}